// Round 9
// baseline (455.054 us; speedup 1.0000x reference)
//
#include <hip/hip_runtime.h>
#include <hip/hip_bf16.h>
#include <cstdint>

// Problem constants: T=512 timesteps/slots, B=64 batch, E=512 embed.
#define TT 512
#define BB 64
#define EE 512

typedef short bf16x8 __attribute__((ext_vector_type(8)));   // 8 bf16 = 4 VGPRs
typedef float f32x4  __attribute__((ext_vector_type(4)));   // MFMA C/D frag

// RNE pack of (a -> low16, b -> high16); compiler emits v_cvt_pk_bf16_f32.
static __device__ __forceinline__ unsigned bpack(float a, float b) {
    union { __hip_bfloat162 h; unsigned u; } cv;
    cv.h = __float22bfloat162_rn(make_float2(a, b));
    return cv.u;
}

// clamp to [0,1] -- single v_med3_f32 (ISA clamp idiom).
static __device__ __forceinline__ float clamp01(float x) {
    return fminf(fmaxf(x, 0.f), 1.f);
}

// Barrier that does NOT drain vmcnt: LDS traffic is made visible
// (lgkmcnt(0)), in-flight global register prefetches stay outstanding.
static __device__ __forceinline__ void barrier_lds_only() {
    asm volatile("s_waitcnt lgkmcnt(0)" ::: "memory");
    __builtin_amdgcn_s_barrier();
}

// ---------------------------------------------------------------------------
// R1 structure (best measured: 46.2 us) with the A-tile LDS path DELETED:
// A-fragments are computed in registers, directly in MFMA layout.
//   Post-R8 accounting: interval ~2750 cy is a dependency chain through the
//   LDS pipe (48 KB/block-interval, ~55% busy incl. 2.65M conflict cycles);
//   HBM 45%, VALU 21%, MFMA 8%. Removing As cuts LDS traffic in HALF
//   (A-writes 8KB + A-frag reads 16KB gone) and removes the A-side lgkm
//   dependency, paying ~2x VALU on an idle pipe.
//   Correctness of reg-A in-fragment-layout (row=lane&15, k=quad*8+j) was
//   proven by R3 (passed). R4/R8 lesson: keep VGPRs < 128 -- af liveness is
//   one fragment at a time (compute af[mi] -> 4 MFMAs -> next mi).
//
//   wave-0 prologue: queue scan (closed form, max-plus wave scan) -> Rs/CUs.
//     Q(t) = relu(Q(t-1) - u_t) + d_t,  CU(t) = sum u,  R(t) = Q(t) + CU(t)
//   main: out[t,b,e] = sum_i C[t,i] * V[i,b,e],
//     C[t,i] = clamp01(R_i - CU_t) - clamp01(R_{i-1} - CU_t)   (0 for i>t)
//
// 128m x 128n block tile, BK=32, 4 waves (2x2), 64x64/wave, acc[4][4].
// Triangular: tile MI needs kiters = 4(MI+1); MI = (g+s)&3 -> a CU's 4
// resident blocks (ids 256 apart) get MI {0,1,2,3}: per-CU work balanced.
// Per kk: B-fill | prefetch | barrier | bf+rv reads | barrier | af-compute
// + MFMA (overlaps other blocks' writes). Grid 1024 x 256, 4 blocks/CU
// (LDS now only 14.3 KB). vmcnt never drained (1-chunk-ahead prefetch).
// ---------------------------------------------------------------------------
__global__ __launch_bounds__(256, 4) void gemm_fused_kernel(
        const float* __restrict__ V,    // [T(i)][B][E]
        const float* __restrict__ U,    // [T][B]
        const float* __restrict__ D,    // [T][B]
        float* __restrict__ out) {      // [T(t)][B][E]
    const int id  = blockIdx.x;
    const int xcd = id & 7;
    const int g   = id >> 8;            // 0..3 stride-256 dispatch group
    const int s   = (id >> 3) & 31;     // 0..31
    const int MI  = (g + s) & 3;        // balanced MI per CU
    const int b   = xcd + 8 * (s & 7);  // b % 8 == xcd
    const int n0  = (s >> 3) * 128;
    const int m0  = MI * 128;
    const int kiters = 4 * (MI + 1);    // k0 < m0 + 128

    __shared__ __align__(16) unsigned short Bs[128 * 40];  // [e][i] stride 40
    __shared__ __align__(16) float Rs[TT];
    __shared__ __align__(16) float CUs[TT];

    const int tid  = threadIdx.x;
    const int wave = tid >> 6;
    const int lane = tid & 63;

    // B-fill: thread owns 8k x 2e micro-tile (R1-exact).
    const int b_k8 = wave * 8;            // 0..24
    const int b_e2 = lane * 2;            // 0..126
    // Fragments: 2x2 waves, 64x64 per wave.
    const int wm   = (wave >> 1) * 64;
    const int wn   = (wave & 1) * 64;
    const int frow = lane & 15;
    const int quad = lane >> 4;

    const float* Vb = V + (size_t)b * EE + n0 + b_e2;   // + k*(BB*EE)

    // Prefetch chunk 0; latency hides under the scan.
    float2 v[8];
    #pragma unroll
    for (int r = 0; r < 8; ++r)
        v[r] = *(const float2*)(Vb + (size_t)(b_k8 + r) * (BB * EE));

    // ---- In-block scan (wave 0 only): R/CU for batch b into LDS ----
    if (wave == 0) {
        float u[8], d[8];
        #pragma unroll
        for (int j = 0; j < 8; ++j) {
            u[j] = U[(lane * 8 + j) * BB + b];
            d[j] = D[(lane * 8 + j) * BB + b];
        }
        float A = 0.f, Bv = -1e30f, S = 0.f;
        #pragma unroll
        for (int j = 0; j < 8; ++j) {
            const float a = d[j] - u[j];
            Bv = fmaxf(Bv + a, d[j]);
            A += a;
            S += u[j];
        }
        #pragma unroll
        for (int off = 1; off < 64; off <<= 1) {
            const float Ap = __shfl_up(A, off);
            const float Bp = __shfl_up(Bv, off);
            const float Sp = __shfl_up(S, off);
            if (lane >= off) {
                Bv = fmaxf(Bp + A, Bv);
                A  = A + Ap;
                S  = S + Sp;
            }
        }
        float Aex = __shfl_up(A, 1), Bex = __shfl_up(Bv, 1), Sex = __shfl_up(S, 1);
        if (lane == 0) { Aex = 0.f; Bex = -1e30f; Sex = 0.f; }
        float Q  = fmaxf(Aex, Bex);
        float cu = Sex;
        float rv[8], cv[8];
        #pragma unroll
        for (int j = 0; j < 8; ++j) {
            cu += u[j];
            Q = fmaxf(Q - u[j], 0.f) + d[j];
            rv[j] = Q + cu;
            cv[j] = cu;
        }
        *(float4*)(Rs  + lane * 8)     = make_float4(rv[0], rv[1], rv[2], rv[3]);
        *(float4*)(Rs  + lane * 8 + 4) = make_float4(rv[4], rv[5], rv[6], rv[7]);
        *(float4*)(CUs + lane * 8)     = make_float4(cv[0], cv[1], cv[2], cv[3]);
        *(float4*)(CUs + lane * 8 + 4) = make_float4(cv[4], cv[5], cv[6], cv[7]);
    }
    barrier_lds_only();                   // publishes Rs/CUs; v stays in flight

    // Per-row CU for this wave's 4 m-fragments (broadcast-free, resident).
    float cu_m[4];
    #pragma unroll
    for (int mi = 0; mi < 4; ++mi)
        cu_m[mi] = CUs[m0 + wm + mi * 16 + frow];

    f32x4 acc[4][4];
    #pragma unroll
    for (int mi = 0; mi < 4; ++mi)
        #pragma unroll
        for (int ni = 0; ni < 4; ++ni)
            acc[mi][ni] = f32x4{0.f, 0.f, 0.f, 0.f};

    for (int kk = 0; kk < kiters; ++kk) {
        const int k0 = kk * 32;

        // ---- B-fill: pack prefetched 8k x 2e of V, register transpose ----
        {
            uint4 p0, p1;
            p0.x = bpack(v[0].x, v[1].x); p0.y = bpack(v[2].x, v[3].x);
            p0.z = bpack(v[4].x, v[5].x); p0.w = bpack(v[6].x, v[7].x);
            p1.x = bpack(v[0].y, v[1].y); p1.y = bpack(v[2].y, v[3].y);
            p1.z = bpack(v[4].y, v[5].y); p1.w = bpack(v[6].y, v[7].y);
            *(uint4*)(Bs + b_e2 * 40 + b_k8)       = p0;
            *(uint4*)(Bs + (b_e2 + 1) * 40 + b_k8) = p1;
        }

        // ---- Prefetch next chunk (registers; in flight across barriers) ----
        if (kk + 1 < kiters) {
            const float* vp = Vb + (size_t)((kk + 1) * 32 + b_k8) * (BB * EE);
            #pragma unroll
            for (int r = 0; r < 8; ++r)
                v[r] = *(const float2*)(vp + (size_t)r * (BB * EE));
        }

        barrier_lds_only();               // publish Bs(kk)

        // ---- Reads: B-frags (LDS) + R values (broadcast) ----
        bf16x8 bf[4];
        #pragma unroll
        for (int ni = 0; ni < 4; ++ni)
            bf[ni] = *(const bf16x8*)(Bs + (wn + ni * 16 + frow) * 40 + quad * 8);
        const int i0 = k0 + quad * 8;
        const float4 r0 = *(const float4*)(Rs + i0);
        const float4 r1 = *(const float4*)(Rs + i0 + 4);
        const float rv[8] = {r0.x, r0.y, r0.z, r0.w, r1.x, r1.y, r1.z, r1.w};
        const float prev = (i0 == 0) ? 0.f : Rs[i0 - 1];

        barrier_lds_only();               // reads done; next writes may overlap

        // ---- A-frags in registers (MFMA layout: row=frow, k=quad*8+j) ----
        if (k0 < m0) {                    // strictly below diagonal: no mask
            #pragma unroll
            for (int mi = 0; mi < 4; ++mi) {
                const float cu = cu_m[mi];
                float pvp = clamp01(prev - cu);
                float c[8];
                #pragma unroll
                for (int j = 0; j < 8; ++j) {
                    const float pv = clamp01(rv[j] - cu);
                    c[j] = pv - pvp;
                    pvp = pv;
                }
                union { unsigned u[4]; bf16x8 vv; } af;
                af.u[0] = bpack(c[0], c[1]); af.u[1] = bpack(c[2], c[3]);
                af.u[2] = bpack(c[4], c[5]); af.u[3] = bpack(c[6], c[7]);
                #pragma unroll
                for (int ni = 0; ni < 4; ++ni)
                    acc[mi][ni] = __builtin_amdgcn_mfma_f32_16x16x32_bf16(
                        af.vv, bf[ni], acc[mi][ni], 0, 0, 0);
            }
        } else {                          // diagonal chunk: zero for i > t
            #pragma unroll
            for (int mi = 0; mi < 4; ++mi) {
                const float cu = cu_m[mi];
                const int rel = (m0 + wm + mi * 16 + frow) - i0;  // keep j <= rel
                float pvp = clamp01(prev - cu);
                float c[8];
                #pragma unroll
                for (int j = 0; j < 8; ++j) {
                    const float pv = clamp01(rv[j] - cu);
                    c[j] = (j <= rel) ? (pv - pvp) : 0.f;
                    pvp = pv;
                }
                union { unsigned u[4]; bf16x8 vv; } af;
                af.u[0] = bpack(c[0], c[1]); af.u[1] = bpack(c[2], c[3]);
                af.u[2] = bpack(c[4], c[5]); af.u[3] = bpack(c[6], c[7]);
                #pragma unroll
                for (int ni = 0; ni < 4; ++ni)
                    acc[mi][ni] = __builtin_amdgcn_mfma_f32_16x16x32_bf16(
                        af.vv, bf[ni], acc[mi][ni], 0, 0, 0);
            }
        }
    }

    // Epilogue: C/D layout col=lane&15, row=quad*4+r (m89/m91 verified).
    #pragma unroll
    for (int mi = 0; mi < 4; ++mi) {
        #pragma unroll
        for (int r = 0; r < 4; ++r) {
            const int t = m0 + wm + mi * 16 + quad * 4 + r;
            float* orow = out + ((size_t)t * BB + b) * EE + n0 + wn + frow;
            #pragma unroll
            for (int ni = 0; ni < 4; ++ni)
                orow[ni * 16] = acc[mi][ni][r];
        }
    }
}

extern "C" void kernel_launch(void* const* d_in, const int* in_sizes, int n_in,
                              void* d_out, int out_size, void* d_ws, size_t ws_size,
                              hipStream_t stream) {
    const float* V = (const float*)d_in[0];   // [T,B,E]
    const float* U = (const float*)d_in[1];   // [T,B]
    const float* D = (const float*)d_in[2];   // [T,B]
    float* out = (float*)d_out;               // [T,B,E]

    gemm_fused_kernel<<<dim3(1024), dim3(256), 0, stream>>>(V, U, D, out);
}